// Round 7
// baseline (301.863 us; speedup 1.0000x reference)
//
#include <hip/hip_runtime.h>
#include <hip/hip_bf16.h>

// b=2048, m=8192, d=1024, 2d=2048, out=1000. fp32 in/out, bf16 MFMA GEMMs.
// Z (cosine scores) in fp16. sparsemax+gather fused (support ~100/8192).
// GEMM: BMxBN tile (64x64 per wave), BK=32, XOR swizzle on the GLOBAL address
// (LDS dest stays lane-contiguous as global_load_lds requires),
// shfl-packed 16-bit epilogue stores (8B/lane-quad, kills write inflation).

#define TPB 256
#define CAP 1024   // compact-list capacity; fallback path if exceeded

typedef __bf16 bf16x8 __attribute__((ext_vector_type(8)));
typedef float  f32x4  __attribute__((ext_vector_type(4)));

typedef const __attribute__((address_space(1))) void* gas_ptr;
typedef __attribute__((address_space(3))) void*       las_ptr;

__device__ __forceinline__ unsigned short f2bf(float f) {
    __hip_bfloat16 h = __float2bfloat16(f);
    union { __hip_bfloat16 h; unsigned short s; } u; u.h = h; return u.s;
}
__device__ __forceinline__ float bf2f(unsigned short s) {
    union { unsigned int b; float f; } u; u.b = (unsigned int)s << 16; return u.f;
}
__device__ __forceinline__ unsigned short f2h(float f) {
    union { _Float16 h; unsigned short s; } u; u.h = (_Float16)f; return u.s;
}
__device__ __forceinline__ float h2f(unsigned short s) {
    union { unsigned short s; _Float16 h; } u; u.s = s; return (float)u.h;
}

__device__ __forceinline__ float block_reduce_sum(float v, float* sred) {
    #pragma unroll
    for (int off = 32; off > 0; off >>= 1) v += __shfl_down(v, off, 64);
    int lane = threadIdx.x & 63, wid = threadIdx.x >> 6;
    if (lane == 0) sred[wid] = v;
    __syncthreads();
    if (threadIdx.x == 0) sred[0] = sred[0] + sred[1] + sred[2] + sred[3];
    __syncthreads();
    float r = sred[0];
    __syncthreads();
    return r;
}

__device__ __forceinline__ void block_reduce_sum2(float& a, float& b, float* sred) {
    #pragma unroll
    for (int off = 32; off > 0; off >>= 1) {
        a += __shfl_down(a, off, 64);
        b += __shfl_down(b, off, 64);
    }
    int lane = threadIdx.x & 63, wid = threadIdx.x >> 6;
    if (lane == 0) { sred[wid] = a; sred[4 + wid] = b; }
    __syncthreads();
    if (threadIdx.x == 0) {
        sred[0] = sred[0] + sred[1] + sred[2] + sred[3];
        sred[4] = sred[4] + sred[5] + sred[6] + sred[7];
    }
    __syncthreads();
    a = sred[0]; b = sred[4];
    __syncthreads();
}

// Merged: rows [0,nrow0) normalize X0->Y0; rest X1->Y1 (+norm).
__global__ __launch_bounds__(TPB) void normalize_rows_bf16(const float* __restrict__ X0,
                                                           unsigned short* __restrict__ Y0,
                                                           const float* __restrict__ X1,
                                                           unsigned short* __restrict__ Y1,
                                                           float* __restrict__ norms1,
                                                           int nrow0, int cols) {
    __shared__ float sred[4];
    int r = blockIdx.x, tid = threadIdx.x;
    const float* X; unsigned short* Y; float* nn; int row;
    if (r < nrow0) { X = X0; Y = Y0; nn = nullptr; row = r; }
    else           { X = X1; Y = Y1; nn = norms1; row = r - nrow0; }
    const float4* x4 = (const float4*)(X + (size_t)row * cols);
    ushort4* y4 = (ushort4*)(Y + (size_t)row * cols);
    int n4 = cols >> 2;
    float ss = 0.f;
    for (int i = tid; i < n4; i += TPB) {
        float4 v = x4[i];
        ss += v.x * v.x + v.y * v.y + v.z * v.z + v.w * v.w;
    }
    float tot = block_reduce_sum(ss, sred);
    float nrm = sqrtf(tot + 1e-6f);
    float inv = 1.0f / nrm;
    if (nn && tid == 0) nn[row] = nrm;
    for (int i = tid; i < n4; i += TPB) {
        float4 v = x4[i];
        ushort4 o;
        o.x = f2bf(v.x * inv); o.y = f2bf(v.y * inv);
        o.z = f2bf(v.z * inv); o.w = f2bf(v.w * inv);
        y4[i] = o;
    }
}

// Two transposes (W1 and W2) in one launch. in fp32 [R][C] -> out bf16 [Cpad][R].
__device__ __forceinline__ void tc_body(const float* in, unsigned short* out,
                                        int R, int C, int Cpad, int bx, int by) {
    __shared__ float t[32][33];
    int x = threadIdx.x & 31, y = threadIdx.x >> 5;
    int r0 = by * 32, c0 = bx * 32;
    #pragma unroll
    for (int yy = y; yy < 32; yy += 8) {
        int c = c0 + x;
        t[yy][x] = (c < C) ? in[(size_t)(r0 + yy) * C + c] : 0.f;
    }
    __syncthreads();
    #pragma unroll
    for (int yy = y; yy < 32; yy += 8) {
        int c = c0 + yy;
        if (c < Cpad)
            out[(size_t)c * R + r0 + x] = f2bf(t[x][yy]);
    }
}

__global__ __launch_bounds__(TPB) void transpose_cast2(const float* __restrict__ in1,
                                                       unsigned short* __restrict__ out1,
                                                       int R1, int C1, int Cp1,
                                                       const float* __restrict__ in2,
                                                       unsigned short* __restrict__ out2,
                                                       int R2, int C2, int Cp2,
                                                       int nblk1) {
    int bid = blockIdx.x;
    if (bid < nblk1) {
        int nx = Cp1 / 32;
        tc_body(in1, out1, R1, C1, Cp1, bid % nx, bid / nx);
    } else {
        bid -= nblk1;
        int nx = Cp2 / 32;
        tc_body(in2, out2, R2, C2, Cp2, bid % nx, bid / nx);
    }
}

// Fused sparsemax (Michelot, exact, moment head-start) + gather:
// mv[row] = sum_i sparsemax(z)_i * mem_i = sum_i (z_i - tau) * ynorm_i * yhat_i.
// One block per row. fp16 z row kept raw in LDS (16 KB).
__global__ __launch_bounds__(TPB) void sparsemax_gather(const unsigned short* __restrict__ Zh,
                                                        const float* __restrict__ ynorm,
                                                        const unsigned short* __restrict__ yn,
                                                        unsigned short* __restrict__ mv,
                                                        int m, int d) {
    __shared__ unsigned short szh[8192];   // 16 KB raw fp16
    __shared__ float sred[8];
    __shared__ unsigned short cidx[CAP];
    __shared__ float cval[CAP];
    __shared__ unsigned int lcnt;
    int row = blockIdx.x, tid = threadIdx.x;
    const uint4* zr8 = (const uint4*)(Zh + (size_t)row * m);
    uint4* sz8 = (uint4*)szh;
    int n8 = m >> 3;

    // Pass A: stream + sum + sumsq
    float s = 0.f, q = 0.f;
    for (int i = tid; i < n8; i += TPB) {
        uint4 v = zr8[i];
        sz8[i] = v;
        unsigned int ww[4] = {v.x, v.y, v.z, v.w};
        #pragma unroll
        for (int k = 0; k < 4; ++k) {
            float a = h2f((unsigned short)(ww[k] & 0xffffu));
            float bq = h2f((unsigned short)(ww[k] >> 16));
            s += a + bq; q += a * a + bq * bq;
        }
    }
    if (tid == 0) lcnt = 0;
    block_reduce_sum2(s, q, sred);
    float fm   = (float)m;
    float mean = s / fm;
    float sig  = sqrtf(fmaxf(q / fm - mean * mean, 0.f));
    float tau_s = (s - 1.f) / fm;
    float tau_g = mean + 2.f * sig;

    // Pass B: excess-sum & count at both thresholds
    float Sg = 0.f, cg = 0.f, Ss = 0.f, cs = 0.f;
    for (int i = tid; i < n8; i += TPB) {
        uint4 v = sz8[i];
        unsigned int ww[4] = {v.x, v.y, v.z, v.w};
        #pragma unroll
        for (int k = 0; k < 4; ++k) {
            float a = h2f((unsigned short)(ww[k] & 0xffffu));
            float bq = h2f((unsigned short)(ww[k] >> 16));
            if (a > tau_g) { Sg += a - tau_g; cg += 1.f; }
            if (a > tau_s) { Ss += a - tau_s; cs += 1.f; }
            if (bq > tau_g) { Sg += bq - tau_g; cg += 1.f; }
            if (bq > tau_s) { Ss += bq - tau_s; cs += 1.f; }
        }
    }
    block_reduce_sum2(Sg, cg, sred);
    block_reduce_sum2(Ss, cs, sred);

    float tau_lb, S_act, c_act;
    if (Sg >= 1.f) { tau_lb = tau_g; S_act = Sg + cg * tau_g; c_act = cg; }
    else           { tau_lb = tau_s; S_act = Ss + cs * tau_s; c_act = cs; }
    float tau1 = (S_act - 1.f) / c_act;
    if (tau1 < tau_lb) tau1 = tau_lb;

    // Pass C: compact actives at tau1
    for (int i = tid; i < m; i += TPB) {
        float z = h2f(szh[i]);
        if (z > tau1) {
            unsigned int slot = atomicAdd(&lcnt, 1u);
            if (slot < CAP) { cidx[slot] = (unsigned short)i; cval[slot] = z; }
        }
    }
    __syncthreads();

    int fast = (lcnt <= CAP && lcnt > 0);
    float tau = tau1;
    int n = (int)lcnt;
    if (fast) {
        float prev = -1.f;
        for (int it = 0; it < 64; ++it) {
            float S = 0.f, c = 0.f;
            for (int j = tid; j < n; j += TPB) {
                float z = cval[j];
                if (z > tau) { S += z; c += 1.f; }
            }
            block_reduce_sum2(S, c, sred);
            if (c < 0.5f || c == prev) break;
            tau = (S - 1.f) / c; prev = c;
        }
        // fold norm into weights (<=0 entries become 0, skipped in gather)
        for (int j = tid; j < n; j += TPB) {
            float w = cval[j] - tau;
            cval[j] = (w > 0.f) ? w * ynorm[cidx[j]] : 0.f;
        }
        __syncthreads();
    } else {
        // fallback: full-row Michelot (correct for any input)
        float prev = -1.f;
        for (int it = 0; it < 64; ++it) {
            float S = 0.f, c = 0.f;
            for (int i = tid; i < m; i += TPB) {
                float z = h2f(szh[i]);
                if (z > tau) { S += z; c += 1.f; }
            }
            block_reduce_sum2(S, c, sred);
            if (c < 0.5f || c == prev) break;
            tau = (S - 1.f) / c; prev = c;
        }
    }

    // Gather: two 128-thread groups, each owns 8 cols, alternate entries.
    int g = tid >> 7;            // 0/1
    int c0 = (tid & 127) * 8;    // d = 1024 = 128*8
    float acc[8] = {};
    if (fast) {
        for (int j = g; j < n; j += 2) {
            float w = cval[j];
            if (w <= 0.f) continue;
            int idx = (int)cidx[j];
            uint4 v = *(const uint4*)&yn[(size_t)idx * d + c0];
            unsigned int ww[4] = {v.x, v.y, v.z, v.w};
            #pragma unroll
            for (int k = 0; k < 4; ++k) {
                acc[2 * k]     += w * bf2f((unsigned short)(ww[k] & 0xffffu));
                acc[2 * k + 1] += w * bf2f((unsigned short)(ww[k] >> 16));
            }
        }
    } else {
        for (int i = g; i < m; i += 2) {
            float w = h2f(szh[i]) - tau;
            if (w <= 0.f) continue;
            w *= ynorm[i];
            uint4 v = *(const uint4*)&yn[(size_t)i * d + c0];
            unsigned int ww[4] = {v.x, v.y, v.z, v.w};
            #pragma unroll
            for (int k = 0; k < 4; ++k) {
                acc[2 * k]     += w * bf2f((unsigned short)(ww[k] & 0xffffu));
                acc[2 * k + 1] += w * bf2f((unsigned short)(ww[k] >> 16));
            }
        }
    }
    __syncthreads();
    float* comb = (float*)szh;   // reuse (row data no longer needed)
    if (g == 1) {
        #pragma unroll
        for (int k = 0; k < 8; ++k) comb[(tid & 127) * 8 + k] = acc[k];
    }
    __syncthreads();
    if (g == 0) {
        #pragma unroll
        for (int k = 0; k < 8; ++k) acc[k] += comb[(tid & 127) * 8 + k];
        unsigned int w0 = f2bf(acc[0]) | ((unsigned int)f2bf(acc[1]) << 16);
        unsigned int w1 = f2bf(acc[2]) | ((unsigned int)f2bf(acc[3]) << 16);
        unsigned int w2 = f2bf(acc[4]) | ((unsigned int)f2bf(acc[5]) << 16);
        unsigned int w3 = f2bf(acc[6]) | ((unsigned int)f2bf(acc[7]) << 16);
        uint4 st = {w0, w1, w2, w3};
        *(uint4*)&mv[(size_t)row * d + c0] = st;
    }
}

// C[M][ldc] = A[M][lda] * B^T (+bias)(+relu). B is [Npad][K] bf16 row-major.
// BM x BN tile, each wave owns 64x64, BK=32, swizzle on global addr (LDS dest
// lane-contiguous). Block = (BM/64)*(BN/64) waves — launch MUST match.
// OUTMODE: 0=f32, 1=bf16, 2=f16.
template <int BM, int BN, int OUTMODE, int RELU, int HASBIAS>
__global__ __launch_bounds__((BM / 64) * (BN / 64) * 64)
void gemm_bt(const unsigned short* __restrict__ A,
             const unsigned short* __restrict__ B,
             const float* __restrict__ bias,
             void* __restrict__ C,
             int M, int K, int lda, int NOUT, int ldc) {
    constexpr int NW   = (BM / 64) * (BN / 64);
    constexpr int TPBL = NW * 64;
    __shared__ unsigned short lA[BM * 32];
    __shared__ unsigned short lB[BN * 32];
    int tid = threadIdx.x;
    int lane = tid & 63, wv = tid >> 6;
    int wm = (wv % (BM / 64)) * 64;
    int wn = (wv / (BM / 64)) * 64;
    int lr = lane & 15, kq = lane >> 4;

    int rowBase = blockIdx.y * BM;
    int colBase = blockIdx.x * BN;

    f32x4 acc[4][4] = {};

    for (int k0 = 0; k0 < K; k0 += 32) {
        constexpr int AI = BM * 4 / TPBL;
        #pragma unroll
        for (int l = 0; l < AI; ++l) {
            int li = l * TPBL + tid;
            int row = li >> 2, s0 = li & 3;
            int seg = s0 ^ ((row >> 1) & 3);
            const char* g = (const char*)(A + (size_t)(rowBase + row) * lda + k0) + seg * 16;
            __builtin_amdgcn_global_load_lds((gas_ptr)g, (las_ptr)((char*)lA + li * 16), 16, 0, 0);
        }
        constexpr int BI = BN * 4 / TPBL;
        #pragma unroll
        for (int l = 0; l < BI; ++l) {
            int li = l * TPBL + tid;
            int row = li >> 2, s0 = li & 3;
            int seg = s0 ^ ((row >> 1) & 3);
            const char* g = (const char*)(B + (size_t)(colBase + row) * K + k0) + seg * 16;
            __builtin_amdgcn_global_load_lds((gas_ptr)g, (las_ptr)((char*)lB + li * 16), 16, 0, 0);
        }
        __syncthreads();

        bf16x8 av[4], bv[4];
        #pragma unroll
        for (int i = 0; i < 4; ++i) {
            int row = wm + i * 16 + lr;
            av[i] = *(const bf16x8*)((const char*)lA + row * 64 + ((kq ^ ((row >> 1) & 3)) * 16));
        }
        #pragma unroll
        for (int j = 0; j < 4; ++j) {
            int row = wn + j * 16 + lr;
            bv[j] = *(const bf16x8*)((const char*)lB + row * 64 + ((kq ^ ((row >> 1) & 3)) * 16));
        }
        #pragma unroll
        for (int i = 0; i < 4; ++i)
            #pragma unroll
            for (int j = 0; j < 4; ++j)
                acc[i][j] = __builtin_amdgcn_mfma_f32_16x16x32_bf16(av[i], bv[j], acc[i][j], 0, 0, 0);
        __syncthreads();
    }

    // Epilogue. C/D layout: col = lane&15, row = kq*4+r.
    float* Cf = (float*)C;
    unsigned short* Cb = (unsigned short*)C;
    bool fullN = (colBase + BN) <= NOUT;
    #pragma unroll
    for (int j = 0; j < 4; ++j) {
        int col = colBase + wn + j * 16 + lr;
        float bv_ = (HASBIAS && col < NOUT) ? bias[col] : 0.f;
        #pragma unroll
        for (int i = 0; i < 4; ++i) {
            #pragma unroll
            for (int r = 0; r < 4; ++r) {
                int row = rowBase + wm + i * 16 + kq * 4 + r;
                float v = acc[i][j][r] + bv_;
                if (RELU) v = fmaxf(v, 0.f);
                if (OUTMODE == 0) {
                    float p = __shfl_xor(v, 1, 64);
                    if (fullN) {
                        if (!(lr & 1)) { float2 st = {v, p}; *(float2*)&Cf[(size_t)row * ldc + col] = st; }
                    } else if (col < NOUT) {
                        Cf[(size_t)row * ldc + col] = v;
                    }
                } else {
                    unsigned int hh = (OUTMODE == 1) ? (unsigned int)f2bf(v) : (unsigned int)f2h(v);
                    unsigned int p1 = (unsigned int)__shfl_xor((int)hh, 1, 64);
                    unsigned int u = (hh & 0xffffu) | (p1 << 16);
                    unsigned int p2 = (unsigned int)__shfl_xor((int)u, 2, 64);
                    if (fullN) {
                        if (!(lr & 3)) { uint2 st = {u, p2}; *(uint2*)&Cb[(size_t)row * ldc + col] = st; }
                    } else if (col < NOUT) {
                        Cb[(size_t)row * ldc + col] = (unsigned short)hh;
                    }
                }
            }
        }
    }
}

extern "C" void kernel_launch(void* const* d_in, const int* in_sizes, int n_in,
                              void* d_out, int out_size, void* d_ws, size_t ws_size,
                              hipStream_t stream) {
    const float* enc = (const float*)d_in[0];   // [b, d]
    const float* mem = (const float*)d_in[1];   // [m, d]
    const float* W1  = (const float*)d_in[2];   // [d, 2d]
    const float* b1  = (const float*)d_in[3];   // [2d]
    const float* W2  = (const float*)d_in[4];   // [2d, out]
    const float* b2  = (const float*)d_in[5];   // [out]

    const int d    = in_sizes[3] / 2;           // 1024
    const int b    = in_sizes[0] / d;           // 2048
    const int m    = in_sizes[1] / d;           // 8192
    const int d2   = in_sizes[3];               // 2048
    const int outN = in_sizes[5];               // 1000
    const int outPad = 1024;

    unsigned short* xn    = (unsigned short*)d_ws;                    // [b][d] bf16
    unsigned short* yn    = xn  + (size_t)b * d;                      // [m][d] bf16
    float*          ynorm = (float*)(yn + (size_t)m * d);             // [m] fp32
    unsigned short* W1T   = (unsigned short*)(ynorm + m);             // [2d][d] bf16
    unsigned short* W2T   = W1T + (size_t)d2 * d;                     // [outPad][2d] bf16
    unsigned short* Zh    = W2T + (size_t)outPad * d2;                // [b][m] fp16
    unsigned short* mv    = Zh + (size_t)b * m;                       // [b][d] bf16
    unsigned short* h     = mv + (size_t)b * d;                       // [b][2d] bf16

    // normalize enc->xn and mem->yn (+norms) in one launch
    normalize_rows_bf16<<<b + m, TPB, 0, stream>>>(enc, xn, mem, yn, ynorm, b, d);

    // W1 [d][2d]->W1T [2d][d]  and  W2 [2d][outN]->W2T [outPad][2d] in one launch
    int nblk1 = (d2 / 32) * (d / 32);
    int nblk2 = (outPad / 32) * (d2 / 32);
    transpose_cast2<<<nblk1 + nblk2, TPB, 0, stream>>>(W1, W1T, d, d2, d2,
                                                       W2, W2T, d2, outN, outPad, nblk1);

    // Z = xn * yn^T  [b][m] fp16 (cosine sim; sparsemax is shift-invariant).
    // BM=256, 8 waves -> 512 threads (matches launch_bounds).
    gemm_bt<256, 128, 2, 0, 0><<<dim3(m / 128, b / 256), 512, 0, stream>>>(
        xn, yn, nullptr, Zh, b, d, d, m, m);

    // fused sparsemax + gather -> mv
    sparsemax_gather<<<b, TPB, 0, stream>>>(Zh, ynorm, yn, mv, m, d);

    // h = relu(mv * W1 + b1)  [b][2d] bf16  (4 waves -> 256 threads)
    gemm_bt<128, 128, 1, 1, 1><<<dim3(d2 / 128, b / 128), 256, 0, stream>>>(
        mv, W1T, b1, h, b, d, d, d2, d2);

    // out = h * W2 + b2  [b][outN] fp32  (2 waves -> 128 threads, NOT 256)
    gemm_bt<128, 64, 0, 0, 1><<<dim3(outPad / 64, b / 128), 128, 0, stream>>>(
        h, W2T, b2, d_out, b, d2, d2, outN, outN);
}

// Round 9
// 279.913 us; speedup vs baseline: 1.0784x; 1.0784x over previous
//
#include <hip/hip_runtime.h>
#include <hip/hip_bf16.h>

// b=2048, m=8192, d=1024, 2d=2048, out=1000. fp32 in/out, bf16 MFMA GEMMs.
// Z (cosine scores) in fp16. sparsemax+gather fused; gather reads bf16 rows
// (fp8 gather tried r8: absmax 1.46e-2 > 1.18e-2 threshold — reverted).
// GEMM: BMxBN block, WMxWN wave tiles, BK=64, XOR-swizzled LDS staging
// (0 bank conflicts, measured r5), shfl-packed epilogue stores.

#define TPB 256
#define CAP 1024   // compact-list capacity; fallback path if exceeded

typedef __bf16 bf16x8 __attribute__((ext_vector_type(8)));
typedef float  f32x4  __attribute__((ext_vector_type(4)));

typedef const __attribute__((address_space(1))) void* gas_ptr;
typedef __attribute__((address_space(3))) void*       las_ptr;

__device__ __forceinline__ unsigned short f2bf(float f) {
    __hip_bfloat16 h = __float2bfloat16(f);
    union { __hip_bfloat16 h; unsigned short s; } u; u.h = h; return u.s;
}
__device__ __forceinline__ float bf2f(unsigned short s) {
    union { unsigned int b; float f; } u; u.b = (unsigned int)s << 16; return u.f;
}
__device__ __forceinline__ unsigned short f2h(float f) {
    union { _Float16 h; unsigned short s; } u; u.h = (_Float16)f; return u.s;
}
__device__ __forceinline__ float h2f(unsigned short s) {
    union { unsigned short s; _Float16 h; } u; u.s = s; return (float)u.h;
}

__device__ __forceinline__ float block_reduce_sum(float v, float* sred) {
    #pragma unroll
    for (int off = 32; off > 0; off >>= 1) v += __shfl_down(v, off, 64);
    int lane = threadIdx.x & 63, wid = threadIdx.x >> 6;
    if (lane == 0) sred[wid] = v;
    __syncthreads();
    if (threadIdx.x == 0) sred[0] = sred[0] + sred[1] + sred[2] + sred[3];
    __syncthreads();
    float r = sred[0];
    __syncthreads();
    return r;
}

__device__ __forceinline__ void block_reduce_sum2(float& a, float& b, float* sred) {
    #pragma unroll
    for (int off = 32; off > 0; off >>= 1) {
        a += __shfl_down(a, off, 64);
        b += __shfl_down(b, off, 64);
    }
    int lane = threadIdx.x & 63, wid = threadIdx.x >> 6;
    if (lane == 0) { sred[wid] = a; sred[4 + wid] = b; }
    __syncthreads();
    if (threadIdx.x == 0) {
        sred[0] = sred[0] + sred[1] + sred[2] + sred[3];
        sred[4] = sred[4] + sred[5] + sred[6] + sred[7];
    }
    __syncthreads();
    a = sred[0]; b = sred[4];
    __syncthreads();
}

// Merged: rows [0,nrow0) normalize X0->Y0 (bf16); rest X1->Y1 (bf16) + norm.
__global__ __launch_bounds__(TPB) void normalize_rows_bf16(const float* __restrict__ X0,
                                                           unsigned short* __restrict__ Y0,
                                                           const float* __restrict__ X1,
                                                           unsigned short* __restrict__ Y1,
                                                           float* __restrict__ norms1,
                                                           int nrow0, int cols) {
    __shared__ float sred[4];
    int r = blockIdx.x, tid = threadIdx.x;
    const float* X; unsigned short* Y; float* nn; int row;
    if (r < nrow0) { X = X0; Y = Y0; nn = nullptr; row = r; }
    else           { X = X1; Y = Y1; nn = norms1; row = r - nrow0; }
    const float4* x4 = (const float4*)(X + (size_t)row * cols);
    ushort4* y4 = (ushort4*)(Y + (size_t)row * cols);
    int n4 = cols >> 2;
    float ss = 0.f;
    for (int i = tid; i < n4; i += TPB) {
        float4 v = x4[i];
        ss += v.x * v.x + v.y * v.y + v.z * v.z + v.w * v.w;
    }
    float tot = block_reduce_sum(ss, sred);
    float nrm = sqrtf(tot + 1e-6f);
    float inv = 1.0f / nrm;
    if (nn && tid == 0) nn[row] = nrm;
    for (int i = tid; i < n4; i += TPB) {
        float4 v = x4[i];
        ushort4 o;
        o.x = f2bf(v.x * inv); o.y = f2bf(v.y * inv);
        o.z = f2bf(v.z * inv); o.w = f2bf(v.w * inv);
        y4[i] = o;
    }
}

// Two transposes (W1 and W2) in one launch. in fp32 [R][C] -> out bf16 [Cpad][R].
__device__ __forceinline__ void tc_body(const float* in, unsigned short* out,
                                        int R, int C, int Cpad, int bx, int by) {
    __shared__ float t[32][33];
    int x = threadIdx.x & 31, y = threadIdx.x >> 5;
    int r0 = by * 32, c0 = bx * 32;
    #pragma unroll
    for (int yy = y; yy < 32; yy += 8) {
        int c = c0 + x;
        t[yy][x] = (c < C) ? in[(size_t)(r0 + yy) * C + c] : 0.f;
    }
    __syncthreads();
    #pragma unroll
    for (int yy = y; yy < 32; yy += 8) {
        int c = c0 + yy;
        if (c < Cpad)
            out[(size_t)c * R + r0 + x] = f2bf(t[x][yy]);
    }
}

__global__ __launch_bounds__(TPB) void transpose_cast2(const float* __restrict__ in1,
                                                       unsigned short* __restrict__ out1,
                                                       int R1, int C1, int Cp1,
                                                       const float* __restrict__ in2,
                                                       unsigned short* __restrict__ out2,
                                                       int R2, int C2, int Cp2,
                                                       int nblk1) {
    int bid = blockIdx.x;
    if (bid < nblk1) {
        int nx = Cp1 / 32;
        tc_body(in1, out1, R1, C1, Cp1, bid % nx, bid / nx);
    } else {
        bid -= nblk1;
        int nx = Cp2 / 32;
        tc_body(in2, out2, R2, C2, Cp2, bid % nx, bid / nx);
    }
}

// Fused sparsemax (Michelot, exact, moment head-start) + bf16 gather:
// mv[row] = sum_i sparsemax(z)_i * mem_i = sum_i (z_i - tau) * ynorm_i * yhat_i.
__global__ __launch_bounds__(TPB) void sparsemax_gather(const unsigned short* __restrict__ Zh,
                                                        const float* __restrict__ ynorm,
                                                        const unsigned short* __restrict__ yn,
                                                        unsigned short* __restrict__ mv,
                                                        int m, int d) {
    __shared__ unsigned short szh[8192];   // 16 KB raw fp16
    __shared__ float sred[8];
    __shared__ unsigned short cidx[CAP];
    __shared__ float cval[CAP];
    __shared__ unsigned int lcnt;
    int row = blockIdx.x, tid = threadIdx.x;
    const uint4* zr8 = (const uint4*)(Zh + (size_t)row * m);
    uint4* sz8 = (uint4*)szh;
    int n8 = m >> 3;

    // Pass A: stream + sum + sumsq
    float s = 0.f, q = 0.f;
    for (int i = tid; i < n8; i += TPB) {
        uint4 v = zr8[i];
        sz8[i] = v;
        unsigned int ww[4] = {v.x, v.y, v.z, v.w};
        #pragma unroll
        for (int k = 0; k < 4; ++k) {
            float a = h2f((unsigned short)(ww[k] & 0xffffu));
            float bq = h2f((unsigned short)(ww[k] >> 16));
            s += a + bq; q += a * a + bq * bq;
        }
    }
    if (tid == 0) lcnt = 0;
    block_reduce_sum2(s, q, sred);
    float fm   = (float)m;
    float mean = s / fm;
    float sig  = sqrtf(fmaxf(q / fm - mean * mean, 0.f));
    float tau_s = (s - 1.f) / fm;
    float tau_g = mean + 2.f * sig;

    // Pass B: excess-sum & count at both thresholds
    float Sg = 0.f, cg = 0.f, Ss = 0.f, cs = 0.f;
    for (int i = tid; i < n8; i += TPB) {
        uint4 v = sz8[i];
        unsigned int ww[4] = {v.x, v.y, v.z, v.w};
        #pragma unroll
        for (int k = 0; k < 4; ++k) {
            float a = h2f((unsigned short)(ww[k] & 0xffffu));
            float bq = h2f((unsigned short)(ww[k] >> 16));
            if (a > tau_g) { Sg += a - tau_g; cg += 1.f; }
            if (a > tau_s) { Ss += a - tau_s; cs += 1.f; }
            if (bq > tau_g) { Sg += bq - tau_g; cg += 1.f; }
            if (bq > tau_s) { Ss += bq - tau_s; cs += 1.f; }
        }
    }
    block_reduce_sum2(Sg, cg, sred);
    block_reduce_sum2(Ss, cs, sred);

    float tau_lb, S_act, c_act;
    if (Sg >= 1.f) { tau_lb = tau_g; S_act = Sg + cg * tau_g; c_act = cg; }
    else           { tau_lb = tau_s; S_act = Ss + cs * tau_s; c_act = cs; }
    float tau1 = (S_act - 1.f) / c_act;
    if (tau1 < tau_lb) tau1 = tau_lb;

    // Pass C: compact actives at tau1
    for (int i = tid; i < m; i += TPB) {
        float z = h2f(szh[i]);
        if (z > tau1) {
            unsigned int slot = atomicAdd(&lcnt, 1u);
            if (slot < CAP) { cidx[slot] = (unsigned short)i; cval[slot] = z; }
        }
    }
    __syncthreads();

    int fast = (lcnt <= CAP && lcnt > 0);
    float tau = tau1;
    int n = (int)lcnt;
    if (fast) {
        float prev = -1.f;
        for (int it = 0; it < 64; ++it) {
            float S = 0.f, c = 0.f;
            for (int j = tid; j < n; j += TPB) {
                float z = cval[j];
                if (z > tau) { S += z; c += 1.f; }
            }
            block_reduce_sum2(S, c, sred);
            if (c < 0.5f || c == prev) break;
            tau = (S - 1.f) / c; prev = c;
        }
        for (int j = tid; j < n; j += TPB) {
            float w = cval[j] - tau;
            cval[j] = (w > 0.f) ? w * ynorm[cidx[j]] : 0.f;
        }
        __syncthreads();
    } else {
        float prev = -1.f;
        for (int it = 0; it < 64; ++it) {
            float S = 0.f, c = 0.f;
            for (int i = tid; i < m; i += TPB) {
                float z = h2f(szh[i]);
                if (z > tau) { S += z; c += 1.f; }
            }
            block_reduce_sum2(S, c, sred);
            if (c < 0.5f || c == prev) break;
            tau = (S - 1.f) / c; prev = c;
        }
    }

    // Gather (bf16 rows, 2 KB each): two 128-thread groups, 8 cols/thread.
    int g = tid >> 7;
    int c0 = (tid & 127) * 8;    // d = 1024 = 128*8
    float acc[8] = {};
    if (fast) {
        for (int j = g; j < n; j += 2) {
            float w = cval[j];
            if (w <= 0.f) continue;
            int idx = (int)cidx[j];
            uint4 v = *(const uint4*)&yn[(size_t)idx * d + c0];
            unsigned int ww[4] = {v.x, v.y, v.z, v.w};
            #pragma unroll
            for (int k = 0; k < 4; ++k) {
                acc[2 * k]     += w * bf2f((unsigned short)(ww[k] & 0xffffu));
                acc[2 * k + 1] += w * bf2f((unsigned short)(ww[k] >> 16));
            }
        }
    } else {
        for (int i = g; i < m; i += 2) {
            float w = h2f(szh[i]) - tau;
            if (w <= 0.f) continue;
            w *= ynorm[i];
            uint4 v = *(const uint4*)&yn[(size_t)i * d + c0];
            unsigned int ww[4] = {v.x, v.y, v.z, v.w};
            #pragma unroll
            for (int k = 0; k < 4; ++k) {
                acc[2 * k]     += w * bf2f((unsigned short)(ww[k] & 0xffffu));
                acc[2 * k + 1] += w * bf2f((unsigned short)(ww[k] >> 16));
            }
        }
    }
    __syncthreads();
    float* comb = (float*)szh;   // reuse (row data no longer needed)
    if (g == 1) {
        #pragma unroll
        for (int k = 0; k < 8; ++k) comb[(tid & 127) * 8 + k] = acc[k];
    }
    __syncthreads();
    if (g == 0) {
        #pragma unroll
        for (int k = 0; k < 8; ++k) acc[k] += comb[(tid & 127) * 8 + k];
        unsigned int w0 = f2bf(acc[0]) | ((unsigned int)f2bf(acc[1]) << 16);
        unsigned int w1 = f2bf(acc[2]) | ((unsigned int)f2bf(acc[3]) << 16);
        unsigned int w2 = f2bf(acc[4]) | ((unsigned int)f2bf(acc[5]) << 16);
        unsigned int w3 = f2bf(acc[6]) | ((unsigned int)f2bf(acc[7]) << 16);
        uint4 st = {w0, w1, w2, w3};
        *(uint4*)&mv[(size_t)row * d + c0] = st;
    }
}

// C[M][ldc] = A[M][lda] * B^T (+bias)(+relu). B is [Npad][K] bf16 row-major.
// BM x BN block tile, WM x WN wave tiles, BK=64, XOR-swizzled staging
// (swizzle on global addr; LDS dest lane-contiguous). Launch (BM/WM)*(BN/WN)*64 thr.
// OUTMODE: 0=f32, 1=bf16, 2=f16.
template <int BM, int BN, int WM, int WN, int OUTMODE, int RELU, int HASBIAS>
__global__ __launch_bounds__((BM / WM) * (BN / WN) * 64)
void gemm_bt(const unsigned short* __restrict__ A,
             const unsigned short* __restrict__ B,
             const float* __restrict__ bias,
             void* __restrict__ C,
             int M, int K, int lda, int NOUT, int ldc) {
    constexpr int NW   = (BM / WM) * (BN / WN);
    constexpr int TPBL = NW * 64;
    constexpr int ITM  = WM / 16;
    constexpr int ITN  = WN / 16;
    __shared__ unsigned short lA[BM * 64];
    __shared__ unsigned short lB[BN * 64];
    int tid = threadIdx.x;
    int lane = tid & 63, wv = tid >> 6;
    int wm = (wv % (BM / WM)) * WM;
    int wn = (wv / (BM / WM)) * WN;
    int lr = lane & 15, kq = lane >> 4;

    int rowBase = blockIdx.y * BM;
    int colBase = blockIdx.x * BN;

    f32x4 acc[ITM][ITN] = {};

    for (int k0 = 0; k0 < K; k0 += 64) {
        constexpr int AI = BM * 8 / TPBL;
        #pragma unroll
        for (int l = 0; l < AI; ++l) {
            int li = l * TPBL + tid;
            int row = li >> 3, s0 = li & 7;
            int seg = s0 ^ (row & 7);
            const char* gp = (const char*)(A + (size_t)(rowBase + row) * lda + k0) + seg * 16;
            __builtin_amdgcn_global_load_lds((gas_ptr)gp, (las_ptr)((char*)lA + li * 16), 16, 0, 0);
        }
        constexpr int BI = BN * 8 / TPBL;
        #pragma unroll
        for (int l = 0; l < BI; ++l) {
            int li = l * TPBL + tid;
            int row = li >> 3, s0 = li & 7;
            int seg = s0 ^ (row & 7);
            const char* gp = (const char*)(B + (size_t)(colBase + row) * K + k0) + seg * 16;
            __builtin_amdgcn_global_load_lds((gas_ptr)gp, (las_ptr)((char*)lB + li * 16), 16, 0, 0);
        }
        __syncthreads();

        #pragma unroll
        for (int h = 0; h < 2; ++h) {
            bf16x8 av[ITM], bv[ITN];
            #pragma unroll
            for (int i = 0; i < ITM; ++i) {
                int row = wm + i * 16 + lr;
                av[i] = *(const bf16x8*)((const char*)lA + row * 128
                                         + ((((h << 2) | kq) ^ (row & 7)) * 16));
            }
            #pragma unroll
            for (int j = 0; j < ITN; ++j) {
                int row = wn + j * 16 + lr;
                bv[j] = *(const bf16x8*)((const char*)lB + row * 128
                                         + ((((h << 2) | kq) ^ (row & 7)) * 16));
            }
            #pragma unroll
            for (int i = 0; i < ITM; ++i)
                #pragma unroll
                for (int j = 0; j < ITN; ++j)
                    acc[i][j] = __builtin_amdgcn_mfma_f32_16x16x32_bf16(av[i], bv[j], acc[i][j], 0, 0, 0);
        }
        __syncthreads();
    }

    // Epilogue. C/D layout: col = lane&15, row = kq*4+r. Packed stores.
    float* Cf = (float*)C;
    unsigned short* Cb = (unsigned short*)C;
    bool fullN = (colBase + BN) <= NOUT;
    #pragma unroll
    for (int j = 0; j < ITN; ++j) {
        int col = colBase + wn + j * 16 + lr;
        float bv_ = (HASBIAS && col < NOUT) ? bias[col] : 0.f;
        #pragma unroll
        for (int i = 0; i < ITM; ++i) {
            #pragma unroll
            for (int r = 0; r < 4; ++r) {
                int row = rowBase + wm + i * 16 + kq * 4 + r;
                float v = acc[i][j][r] + bv_;
                if (RELU) v = fmaxf(v, 0.f);
                if (OUTMODE == 0) {
                    float p = __shfl_xor(v, 1, 64);
                    if (fullN) {
                        if (!(lr & 1)) { float2 st = {v, p}; *(float2*)&Cf[(size_t)row * ldc + col] = st; }
                    } else if (col < NOUT) {
                        Cf[(size_t)row * ldc + col] = v;
                    }
                } else {
                    unsigned int hh = (OUTMODE == 1) ? (unsigned int)f2bf(v) : (unsigned int)f2h(v);
                    unsigned int p1 = (unsigned int)__shfl_xor((int)hh, 1, 64);
                    unsigned int u = (hh & 0xffffu) | (p1 << 16);
                    unsigned int p2 = (unsigned int)__shfl_xor((int)u, 2, 64);
                    if (fullN) {
                        if (!(lr & 3)) { uint2 st = {u, p2}; *(uint2*)&Cb[(size_t)row * ldc + col] = st; }
                    } else if (col < NOUT) {
                        Cb[(size_t)row * ldc + col] = (unsigned short)hh;
                    }
                }
            }
        }
    }
}

extern "C" void kernel_launch(void* const* d_in, const int* in_sizes, int n_in,
                              void* d_out, int out_size, void* d_ws, size_t ws_size,
                              hipStream_t stream) {
    const float* enc = (const float*)d_in[0];   // [b, d]
    const float* mem = (const float*)d_in[1];   // [m, d]
    const float* W1  = (const float*)d_in[2];   // [d, 2d]
    const float* b1  = (const float*)d_in[3];   // [2d]
    const float* W2  = (const float*)d_in[4];   // [2d, out]
    const float* b2  = (const float*)d_in[5];   // [out]

    const int d    = in_sizes[3] / 2;           // 1024
    const int b    = in_sizes[0] / d;           // 2048
    const int m    = in_sizes[1] / d;           // 8192
    const int d2   = in_sizes[3];               // 2048
    const int outN = in_sizes[5];               // 1000
    const int outPad = 1024;

    unsigned short* xn    = (unsigned short*)d_ws;                    // [b][d] bf16
    unsigned short* yn    = xn  + (size_t)b * d;                      // [m][d] bf16
    float*          ynorm = (float*)(yn + (size_t)m * d);             // [m] fp32
    unsigned short* W1T   = (unsigned short*)(ynorm + m);             // [2d][d] bf16
    unsigned short* W2T   = W1T + (size_t)d2 * d;                     // [outPad][2d] bf16
    unsigned short* Zh    = W2T + (size_t)outPad * d2;                // [b][m] fp16
    unsigned short* mv    = Zh + (size_t)b * m;                       // [b][d] bf16
    unsigned short* h     = mv + (size_t)b * d;                       // [b][2d] bf16

    // normalize enc->xn and mem->yn (+norms) in one launch
    normalize_rows_bf16<<<b + m, TPB, 0, stream>>>(enc, xn, mem, yn, ynorm, b, d);

    // W1 [d][2d]->W1T [2d][d]  and  W2 [2d][outN]->W2T [outPad][2d] in one launch
    int nblk1 = (d2 / 32) * (d / 32);
    int nblk2 = (outPad / 32) * (d2 / 32);
    transpose_cast2<<<nblk1 + nblk2, TPB, 0, stream>>>(W1, W1T, d, d2, d2,
                                                       W2, W2T, d2, outN, outPad, nblk1);

    // Z = xn * yn^T  [b][m] fp16.  BM=256 x BN=128, 8 waves (512 thr).
    gemm_bt<256, 128, 64, 64, 2, 0, 0><<<dim3(m / 128, b / 256), 512, 0, stream>>>(
        xn, yn, nullptr, Zh, b, d, d, m, m);

    // fused sparsemax + bf16 gather -> mv
    sparsemax_gather<<<b, TPB, 0, stream>>>(Zh, ynorm, yn, mv, m, d);

    // h = relu(mv * W1 + b1)  [b][2d] bf16.  4 waves (256 thr).
    gemm_bt<128, 128, 64, 64, 1, 1, 1><<<dim3(d2 / 128, b / 128), 256, 0, stream>>>(
        mv, W1T, b1, h, b, d, d, d2, d2);

    // out = h * W2 + b2  [b][outN] fp32.  32x64 wave tiles -> 4 waves (256 thr).
    gemm_bt<128, 64, 32, 64, 0, 0, 1><<<dim3(outPad / 64, b / 128), 256, 0, stream>>>(
        h, W2T, b2, d_out, b, d2, d2, outN, outN);
}

// Round 10
// 273.800 us; speedup vs baseline: 1.1025x; 1.0223x over previous
//
#include <hip/hip_runtime.h>
#include <hip/hip_bf16.h>

// b=2048, m=8192, d=1024, 2d=2048, out=1000. fp32 in/out, bf16 MFMA GEMMs.
// Z (cosine scores) in fp16. sparsemax+gather fused; gather reads bf16 rows
// (fp8 gather tried r8: absmax 1.46e-2 > 1.18e-2 threshold — reverted).
// r10: gather unrolled x4 (4 loads in flight vs 1 — it was latency-bound at
// VALU 35% / HBM 23% / occ 47%), list-Michelot on wave0 with shuffle reduce.
// GEMM: BMxBN block, WMxWN wave tiles, BK=64, XOR-swizzled LDS staging
// (0 bank conflicts, measured r5), shfl-packed epilogue stores.

#define TPB 256
#define CAP 1024   // compact-list capacity; fallback path if exceeded

typedef __bf16 bf16x8 __attribute__((ext_vector_type(8)));
typedef float  f32x4  __attribute__((ext_vector_type(4)));

typedef const __attribute__((address_space(1))) void* gas_ptr;
typedef __attribute__((address_space(3))) void*       las_ptr;

__device__ __forceinline__ unsigned short f2bf(float f) {
    __hip_bfloat16 h = __float2bfloat16(f);
    union { __hip_bfloat16 h; unsigned short s; } u; u.h = h; return u.s;
}
__device__ __forceinline__ float bf2f(unsigned short s) {
    union { unsigned int b; float f; } u; u.b = (unsigned int)s << 16; return u.f;
}
__device__ __forceinline__ unsigned short f2h(float f) {
    union { _Float16 h; unsigned short s; } u; u.h = (_Float16)f; return u.s;
}
__device__ __forceinline__ float h2f(unsigned short s) {
    union { unsigned short s; _Float16 h; } u; u.s = s; return (float)u.h;
}

__device__ __forceinline__ float block_reduce_sum(float v, float* sred) {
    #pragma unroll
    for (int off = 32; off > 0; off >>= 1) v += __shfl_down(v, off, 64);
    int lane = threadIdx.x & 63, wid = threadIdx.x >> 6;
    if (lane == 0) sred[wid] = v;
    __syncthreads();
    if (threadIdx.x == 0) sred[0] = sred[0] + sred[1] + sred[2] + sred[3];
    __syncthreads();
    float r = sred[0];
    __syncthreads();
    return r;
}

__device__ __forceinline__ void block_reduce_sum2(float& a, float& b, float* sred) {
    #pragma unroll
    for (int off = 32; off > 0; off >>= 1) {
        a += __shfl_down(a, off, 64);
        b += __shfl_down(b, off, 64);
    }
    int lane = threadIdx.x & 63, wid = threadIdx.x >> 6;
    if (lane == 0) { sred[wid] = a; sred[4 + wid] = b; }
    __syncthreads();
    if (threadIdx.x == 0) {
        sred[0] = sred[0] + sred[1] + sred[2] + sred[3];
        sred[4] = sred[4] + sred[5] + sred[6] + sred[7];
    }
    __syncthreads();
    a = sred[0]; b = sred[4];
    __syncthreads();
}

// Merged: rows [0,nrow0) normalize X0->Y0 (bf16); rest X1->Y1 (bf16) + norm.
__global__ __launch_bounds__(TPB) void normalize_rows_bf16(const float* __restrict__ X0,
                                                           unsigned short* __restrict__ Y0,
                                                           const float* __restrict__ X1,
                                                           unsigned short* __restrict__ Y1,
                                                           float* __restrict__ norms1,
                                                           int nrow0, int cols) {
    __shared__ float sred[4];
    int r = blockIdx.x, tid = threadIdx.x;
    const float* X; unsigned short* Y; float* nn; int row;
    if (r < nrow0) { X = X0; Y = Y0; nn = nullptr; row = r; }
    else           { X = X1; Y = Y1; nn = norms1; row = r - nrow0; }
    const float4* x4 = (const float4*)(X + (size_t)row * cols);
    ushort4* y4 = (ushort4*)(Y + (size_t)row * cols);
    int n4 = cols >> 2;
    float ss = 0.f;
    for (int i = tid; i < n4; i += TPB) {
        float4 v = x4[i];
        ss += v.x * v.x + v.y * v.y + v.z * v.z + v.w * v.w;
    }
    float tot = block_reduce_sum(ss, sred);
    float nrm = sqrtf(tot + 1e-6f);
    float inv = 1.0f / nrm;
    if (nn && tid == 0) nn[row] = nrm;
    for (int i = tid; i < n4; i += TPB) {
        float4 v = x4[i];
        ushort4 o;
        o.x = f2bf(v.x * inv); o.y = f2bf(v.y * inv);
        o.z = f2bf(v.z * inv); o.w = f2bf(v.w * inv);
        y4[i] = o;
    }
}

// Two transposes (W1 and W2) in one launch. in fp32 [R][C] -> out bf16 [Cpad][R].
__device__ __forceinline__ void tc_body(const float* in, unsigned short* out,
                                        int R, int C, int Cpad, int bx, int by) {
    __shared__ float t[32][33];
    int x = threadIdx.x & 31, y = threadIdx.x >> 5;
    int r0 = by * 32, c0 = bx * 32;
    #pragma unroll
    for (int yy = y; yy < 32; yy += 8) {
        int c = c0 + x;
        t[yy][x] = (c < C) ? in[(size_t)(r0 + yy) * C + c] : 0.f;
    }
    __syncthreads();
    #pragma unroll
    for (int yy = y; yy < 32; yy += 8) {
        int c = c0 + yy;
        if (c < Cpad)
            out[(size_t)c * R + r0 + x] = f2bf(t[x][yy]);
    }
}

__global__ __launch_bounds__(TPB) void transpose_cast2(const float* __restrict__ in1,
                                                       unsigned short* __restrict__ out1,
                                                       int R1, int C1, int Cp1,
                                                       const float* __restrict__ in2,
                                                       unsigned short* __restrict__ out2,
                                                       int R2, int C2, int Cp2,
                                                       int nblk1) {
    int bid = blockIdx.x;
    if (bid < nblk1) {
        int nx = Cp1 / 32;
        tc_body(in1, out1, R1, C1, Cp1, bid % nx, bid / nx);
    } else {
        bid -= nblk1;
        int nx = Cp2 / 32;
        tc_body(in2, out2, R2, C2, Cp2, bid % nx, bid / nx);
    }
}

__device__ __forceinline__ void acc8(float* acc, float w, uint4 v) {
    unsigned int ww[4] = {v.x, v.y, v.z, v.w};
    #pragma unroll
    for (int k = 0; k < 4; ++k) {
        acc[2 * k]     += w * bf2f((unsigned short)(ww[k] & 0xffffu));
        acc[2 * k + 1] += w * bf2f((unsigned short)(ww[k] >> 16));
    }
}

// Fused sparsemax (Michelot, exact, moment head-start) + bf16 gather:
// mv[row] = sum_i sparsemax(z)_i * mem_i = sum_i (z_i - tau) * ynorm_i * yhat_i.
__global__ __launch_bounds__(TPB) void sparsemax_gather(const unsigned short* __restrict__ Zh,
                                                        const float* __restrict__ ynorm,
                                                        const unsigned short* __restrict__ yn,
                                                        unsigned short* __restrict__ mv,
                                                        int m, int d) {
    __shared__ unsigned short szh[8192];   // 16 KB raw fp16
    __shared__ float sred[8];
    __shared__ unsigned short cidx[CAP];
    __shared__ float cval[CAP];
    __shared__ unsigned int lcnt;
    int row = blockIdx.x, tid = threadIdx.x;
    const uint4* zr8 = (const uint4*)(Zh + (size_t)row * m);
    uint4* sz8 = (uint4*)szh;
    int n8 = m >> 3;

    // Pass A: stream + sum + sumsq
    float s = 0.f, q = 0.f;
    for (int i = tid; i < n8; i += TPB) {
        uint4 v = zr8[i];
        sz8[i] = v;
        unsigned int ww[4] = {v.x, v.y, v.z, v.w};
        #pragma unroll
        for (int k = 0; k < 4; ++k) {
            float a = h2f((unsigned short)(ww[k] & 0xffffu));
            float bq = h2f((unsigned short)(ww[k] >> 16));
            s += a + bq; q += a * a + bq * bq;
        }
    }
    if (tid == 0) lcnt = 0;
    block_reduce_sum2(s, q, sred);
    float fm   = (float)m;
    float mean = s / fm;
    float sig  = sqrtf(fmaxf(q / fm - mean * mean, 0.f));
    float tau_s = (s - 1.f) / fm;
    float tau_g = mean + 2.f * sig;

    // Pass B: excess-sum & count at both thresholds
    float Sg = 0.f, cg = 0.f, Ss = 0.f, cs = 0.f;
    for (int i = tid; i < n8; i += TPB) {
        uint4 v = sz8[i];
        unsigned int ww[4] = {v.x, v.y, v.z, v.w};
        #pragma unroll
        for (int k = 0; k < 4; ++k) {
            float a = h2f((unsigned short)(ww[k] & 0xffffu));
            float bq = h2f((unsigned short)(ww[k] >> 16));
            if (a > tau_g) { Sg += a - tau_g; cg += 1.f; }
            if (a > tau_s) { Ss += a - tau_s; cs += 1.f; }
            if (bq > tau_g) { Sg += bq - tau_g; cg += 1.f; }
            if (bq > tau_s) { Ss += bq - tau_s; cs += 1.f; }
        }
    }
    block_reduce_sum2(Sg, cg, sred);
    block_reduce_sum2(Ss, cs, sred);

    float tau_lb, S_act, c_act;
    if (Sg >= 1.f) { tau_lb = tau_g; S_act = Sg + cg * tau_g; c_act = cg; }
    else           { tau_lb = tau_s; S_act = Ss + cs * tau_s; c_act = cs; }
    float tau1 = (S_act - 1.f) / c_act;
    if (tau1 < tau_lb) tau1 = tau_lb;

    // Pass C: compact actives at tau1
    for (int i = tid; i < m; i += TPB) {
        float z = h2f(szh[i]);
        if (z > tau1) {
            unsigned int slot = atomicAdd(&lcnt, 1u);
            if (slot < CAP) { cidx[slot] = (unsigned short)i; cval[slot] = z; }
        }
    }
    __syncthreads();

    int fast = (lcnt <= CAP && lcnt > 0);
    float tau = tau1;
    int n = (int)lcnt;
    if (fast) {
        // list-Michelot on wave 0 only (n <= 1024): shuffle reductions, no
        // block-wide barriers inside the iteration loop.
        if ((tid >> 6) == 0) {
            int lane = tid & 63;
            float tau_l = tau1, prev = -1.f;
            for (int it = 0; it < 64; ++it) {
                float S = 0.f, c = 0.f;
                for (int jj = lane; jj < n; jj += 64) {
                    float z = cval[jj];
                    if (z > tau_l) { S += z; c += 1.f; }
                }
                #pragma unroll
                for (int off = 32; off > 0; off >>= 1) {
                    S += __shfl_down(S, off, 64);
                    c += __shfl_down(c, off, 64);
                }
                S = __shfl(S, 0, 64);
                c = __shfl(c, 0, 64);
                if (c < 0.5f || c == prev) break;
                tau_l = (S - 1.f) / c; prev = c;
            }
            if (lane == 0) sred[0] = tau_l;
        }
        __syncthreads();
        tau = sred[0];
        // fold norm into weights (<=0 entries become 0; gather is branchless)
        for (int jj = tid; jj < n; jj += TPB) {
            float w = cval[jj] - tau;
            cval[jj] = (w > 0.f) ? w * ynorm[cidx[jj]] : 0.f;
        }
        __syncthreads();
    } else {
        float prev = -1.f;
        for (int it = 0; it < 64; ++it) {
            float S = 0.f, c = 0.f;
            for (int i = tid; i < m; i += TPB) {
                float z = h2f(szh[i]);
                if (z > tau) { S += z; c += 1.f; }
            }
            block_reduce_sum2(S, c, sred);
            if (c < 0.5f || c == prev) break;
            tau = (S - 1.f) / c; prev = c;
        }
    }

    // Gather (bf16 rows, 2 KB each): two 128-thread groups, 8 cols/thread.
    // Fast path unrolled x4: four independent loads in flight per iteration.
    int g = tid >> 7;
    int c0 = (tid & 127) * 8;    // d = 1024 = 128*8
    float acc[8] = {};
    if (fast) {
        int j = g;
        for (; j + 6 < n; j += 8) {
            int i0 = cidx[j],     i1 = cidx[j + 2];
            int i2 = cidx[j + 4], i3 = cidx[j + 6];
            float w0 = cval[j],     w1 = cval[j + 2];
            float w2 = cval[j + 4], w3 = cval[j + 6];
            uint4 v0 = *(const uint4*)&yn[(size_t)i0 * d + c0];
            uint4 v1 = *(const uint4*)&yn[(size_t)i1 * d + c0];
            uint4 v2 = *(const uint4*)&yn[(size_t)i2 * d + c0];
            uint4 v3 = *(const uint4*)&yn[(size_t)i3 * d + c0];
            acc8(acc, w0, v0); acc8(acc, w1, v1);
            acc8(acc, w2, v2); acc8(acc, w3, v3);
        }
        for (; j < n; j += 2) {
            float w = cval[j];
            int idx = (int)cidx[j];
            uint4 v = *(const uint4*)&yn[(size_t)idx * d + c0];
            acc8(acc, w, v);
        }
    } else {
        for (int i = g; i < m; i += 2) {
            float w = h2f(szh[i]) - tau;
            if (w <= 0.f) continue;
            w *= ynorm[i];
            uint4 v = *(const uint4*)&yn[(size_t)i * d + c0];
            acc8(acc, w, v);
        }
    }
    __syncthreads();
    float* comb = (float*)szh;   // reuse (row data no longer needed)
    if (g == 1) {
        #pragma unroll
        for (int k = 0; k < 8; ++k) comb[(tid & 127) * 8 + k] = acc[k];
    }
    __syncthreads();
    if (g == 0) {
        #pragma unroll
        for (int k = 0; k < 8; ++k) acc[k] += comb[(tid & 127) * 8 + k];
        unsigned int w0 = f2bf(acc[0]) | ((unsigned int)f2bf(acc[1]) << 16);
        unsigned int w1 = f2bf(acc[2]) | ((unsigned int)f2bf(acc[3]) << 16);
        unsigned int w2 = f2bf(acc[4]) | ((unsigned int)f2bf(acc[5]) << 16);
        unsigned int w3 = f2bf(acc[6]) | ((unsigned int)f2bf(acc[7]) << 16);
        uint4 st = {w0, w1, w2, w3};
        *(uint4*)&mv[(size_t)row * d + c0] = st;
    }
}

// C[M][ldc] = A[M][lda] * B^T (+bias)(+relu). B is [Npad][K] bf16 row-major.
// BM x BN block tile, WM x WN wave tiles, BK=64, XOR-swizzled staging
// (swizzle on global addr; LDS dest lane-contiguous). Launch (BM/WM)*(BN/WN)*64 thr.
// OUTMODE: 0=f32, 1=bf16, 2=f16.
template <int BM, int BN, int WM, int WN, int OUTMODE, int RELU, int HASBIAS>
__global__ __launch_bounds__((BM / WM) * (BN / WN) * 64)
void gemm_bt(const unsigned short* __restrict__ A,
             const unsigned short* __restrict__ B,
             const float* __restrict__ bias,
             void* __restrict__ C,
             int M, int K, int lda, int NOUT, int ldc) {
    constexpr int NW   = (BM / WM) * (BN / WN);
    constexpr int TPBL = NW * 64;
    constexpr int ITM  = WM / 16;
    constexpr int ITN  = WN / 16;
    __shared__ unsigned short lA[BM * 64];
    __shared__ unsigned short lB[BN * 64];
    int tid = threadIdx.x;
    int lane = tid & 63, wv = tid >> 6;
    int wm = (wv % (BM / WM)) * WM;
    int wn = (wv / (BM / WM)) * WN;
    int lr = lane & 15, kq = lane >> 4;

    int rowBase = blockIdx.y * BM;
    int colBase = blockIdx.x * BN;

    f32x4 acc[ITM][ITN] = {};

    for (int k0 = 0; k0 < K; k0 += 64) {
        constexpr int AI = BM * 8 / TPBL;
        #pragma unroll
        for (int l = 0; l < AI; ++l) {
            int li = l * TPBL + tid;
            int row = li >> 3, s0 = li & 7;
            int seg = s0 ^ (row & 7);
            const char* gp = (const char*)(A + (size_t)(rowBase + row) * lda + k0) + seg * 16;
            __builtin_amdgcn_global_load_lds((gas_ptr)gp, (las_ptr)((char*)lA + li * 16), 16, 0, 0);
        }
        constexpr int BI = BN * 8 / TPBL;
        #pragma unroll
        for (int l = 0; l < BI; ++l) {
            int li = l * TPBL + tid;
            int row = li >> 3, s0 = li & 7;
            int seg = s0 ^ (row & 7);
            const char* gp = (const char*)(B + (size_t)(colBase + row) * K + k0) + seg * 16;
            __builtin_amdgcn_global_load_lds((gas_ptr)gp, (las_ptr)((char*)lB + li * 16), 16, 0, 0);
        }
        __syncthreads();

        #pragma unroll
        for (int h = 0; h < 2; ++h) {
            bf16x8 av[ITM], bv[ITN];
            #pragma unroll
            for (int i = 0; i < ITM; ++i) {
                int row = wm + i * 16 + lr;
                av[i] = *(const bf16x8*)((const char*)lA + row * 128
                                         + ((((h << 2) | kq) ^ (row & 7)) * 16));
            }
            #pragma unroll
            for (int j = 0; j < ITN; ++j) {
                int row = wn + j * 16 + lr;
                bv[j] = *(const bf16x8*)((const char*)lB + row * 128
                                         + ((((h << 2) | kq) ^ (row & 7)) * 16));
            }
            #pragma unroll
            for (int i = 0; i < ITM; ++i)
                #pragma unroll
                for (int j = 0; j < ITN; ++j)
                    acc[i][j] = __builtin_amdgcn_mfma_f32_16x16x32_bf16(av[i], bv[j], acc[i][j], 0, 0, 0);
        }
        __syncthreads();
    }

    // Epilogue. C/D layout: col = lane&15, row = kq*4+r. Packed stores.
    float* Cf = (float*)C;
    unsigned short* Cb = (unsigned short*)C;
    bool fullN = (colBase + BN) <= NOUT;
    #pragma unroll
    for (int j = 0; j < ITN; ++j) {
        int col = colBase + wn + j * 16 + lr;
        float bv_ = (HASBIAS && col < NOUT) ? bias[col] : 0.f;
        #pragma unroll
        for (int i = 0; i < ITM; ++i) {
            #pragma unroll
            for (int r = 0; r < 4; ++r) {
                int row = rowBase + wm + i * 16 + kq * 4 + r;
                float v = acc[i][j][r] + bv_;
                if (RELU) v = fmaxf(v, 0.f);
                if (OUTMODE == 0) {
                    float p = __shfl_xor(v, 1, 64);
                    if (fullN) {
                        if (!(lr & 1)) { float2 st = {v, p}; *(float2*)&Cf[(size_t)row * ldc + col] = st; }
                    } else if (col < NOUT) {
                        Cf[(size_t)row * ldc + col] = v;
                    }
                } else {
                    unsigned int hh = (OUTMODE == 1) ? (unsigned int)f2bf(v) : (unsigned int)f2h(v);
                    unsigned int p1 = (unsigned int)__shfl_xor((int)hh, 1, 64);
                    unsigned int u = (hh & 0xffffu) | (p1 << 16);
                    unsigned int p2 = (unsigned int)__shfl_xor((int)u, 2, 64);
                    if (fullN) {
                        if (!(lr & 3)) { uint2 st = {u, p2}; *(uint2*)&Cb[(size_t)row * ldc + col] = st; }
                    } else if (col < NOUT) {
                        Cb[(size_t)row * ldc + col] = (unsigned short)hh;
                    }
                }
            }
        }
    }
}

extern "C" void kernel_launch(void* const* d_in, const int* in_sizes, int n_in,
                              void* d_out, int out_size, void* d_ws, size_t ws_size,
                              hipStream_t stream) {
    const float* enc = (const float*)d_in[0];   // [b, d]
    const float* mem = (const float*)d_in[1];   // [m, d]
    const float* W1  = (const float*)d_in[2];   // [d, 2d]
    const float* b1  = (const float*)d_in[3];   // [2d]
    const float* W2  = (const float*)d_in[4];   // [2d, out]
    const float* b2  = (const float*)d_in[5];   // [out]

    const int d    = in_sizes[3] / 2;           // 1024
    const int b    = in_sizes[0] / d;           // 2048
    const int m    = in_sizes[1] / d;           // 8192
    const int d2   = in_sizes[3];               // 2048
    const int outN = in_sizes[5];               // 1000
    const int outPad = 1024;

    unsigned short* xn    = (unsigned short*)d_ws;                    // [b][d] bf16
    unsigned short* yn    = xn  + (size_t)b * d;                      // [m][d] bf16
    float*          ynorm = (float*)(yn + (size_t)m * d);             // [m] fp32
    unsigned short* W1T   = (unsigned short*)(ynorm + m);             // [2d][d] bf16
    unsigned short* W2T   = W1T + (size_t)d2 * d;                     // [outPad][2d] bf16
    unsigned short* Zh    = W2T + (size_t)outPad * d2;                // [b][m] fp16
    unsigned short* mv    = Zh + (size_t)b * m;                       // [b][d] bf16
    unsigned short* h     = mv + (size_t)b * d;                       // [b][2d] bf16

    // normalize enc->xn and mem->yn (+norms) in one launch
    normalize_rows_bf16<<<b + m, TPB, 0, stream>>>(enc, xn, mem, yn, ynorm, b, d);

    // W1 [d][2d]->W1T [2d][d]  and  W2 [2d][outN]->W2T [outPad][2d] in one launch
    int nblk1 = (d2 / 32) * (d / 32);
    int nblk2 = (outPad / 32) * (d2 / 32);
    transpose_cast2<<<nblk1 + nblk2, TPB, 0, stream>>>(W1, W1T, d, d2, d2,
                                                       W2, W2T, d2, outN, outPad, nblk1);

    // Z = xn * yn^T  [b][m] fp16.  BM=256 x BN=128, 8 waves (512 thr).
    gemm_bt<256, 128, 64, 64, 2, 0, 0><<<dim3(m / 128, b / 256), 512, 0, stream>>>(
        xn, yn, nullptr, Zh, b, d, d, m, m);

    // fused sparsemax + bf16 gather -> mv
    sparsemax_gather<<<b, TPB, 0, stream>>>(Zh, ynorm, yn, mv, m, d);

    // h = relu(mv * W1 + b1)  [b][2d] bf16.  4 waves (256 thr).
    gemm_bt<128, 128, 64, 64, 1, 1, 1><<<dim3(d2 / 128, b / 128), 256, 0, stream>>>(
        mv, W1T, b1, h, b, d, d, d2, d2);

    // out = h * W2 + b2  [b][outN] fp32.  32x64 wave tiles -> 4 waves (256 thr).
    gemm_bt<128, 64, 32, 64, 0, 0, 1><<<dim3(outPad / 64, b / 128), 256, 0, stream>>>(
        h, W2T, b2, d_out, b, d2, d2, outN, outN);
}